// Round 1
// baseline (327.156 us; speedup 1.0000x reference)
//
#include <hip/hip_runtime.h>
#include <hip/hip_bf16.h>

typedef __attribute__((ext_vector_type(8))) short short8;
typedef __attribute__((ext_vector_type(4))) float f32x4;
typedef __attribute__((ext_vector_type(16))) float f32x16;

#define WS_PART 0u          // 256 * float2 partials
#define WS_STATS 4096u      // 8 * float2 (mean, rstd)
#define WS_WT 8192u         // 4*256*256 bf16 = 512KB
#define WS_Q  (1u<<20)
#define WS_K  (WS_Q + 16777216u)
#define WS_V  (WS_K + 16777216u)
#define WS_VT (WS_V + 16777216u)
#define WS_O  (WS_VT + 16777216u)

__device__ __forceinline__ unsigned short f2bf(float f) {
  unsigned int u = __builtin_bit_cast(unsigned int, f);
  u += 0x7fffu + ((u >> 16) & 1u);
  return (unsigned short)(u >> 16);
}

// ---------------- weight transpose: wT[m][d][c] = bf16(w_m[c][d]) ----------------
__global__ void k_wt(const float* __restrict__ wq, const float* __restrict__ wk,
                     const float* __restrict__ wv, const float* __restrict__ wp,
                     unsigned short* __restrict__ wT) {
  int m = blockIdx.x >> 8;
  int c = blockIdx.x & 255;
  const float* w = (m == 0) ? wq : (m == 1) ? wk : (m == 2) ? wv : wp;
  int d = threadIdx.x;
  wT[(size_t)(m * 256 + d) * 256 + c] = f2bf(w[c * 256 + d]);
}

// ---------------- GroupNorm stats (per batch over 1M elements) ----------------
__global__ void k_gn_part(const float* __restrict__ x, float2* __restrict__ part) {
  int b = blockIdx.x >> 5, seg = blockIdx.x & 31;
  const float4* xp = (const float4*)(x + ((size_t)b << 20) + ((size_t)seg << 15));
  float s = 0.f, sq = 0.f;
  for (int i = 0; i < 32; ++i) {
    float4 v = xp[threadIdx.x + i * 256];
    s += v.x + v.y + v.z + v.w;
    sq += v.x * v.x + v.y * v.y + v.z * v.z + v.w * v.w;
  }
  for (int m = 1; m <= 32; m <<= 1) { s += __shfl_xor(s, m); sq += __shfl_xor(sq, m); }
  __shared__ float2 red[4];
  int w = threadIdx.x >> 6;
  if ((threadIdx.x & 63) == 0) red[w] = make_float2(s, sq);
  __syncthreads();
  if (threadIdx.x == 0) {
    float S = 0.f, Q = 0.f;
    for (int i = 0; i < 4; ++i) { S += red[i].x; Q += red[i].y; }
    part[blockIdx.x] = make_float2(S, Q);
  }
}

__global__ void k_gn_stats(const float2* __restrict__ part, float2* __restrict__ stats) {
  int b = blockIdx.x, t = threadIdx.x;
  float s = 0.f, sq = 0.f;
  if (t < 32) { float2 p = part[b * 32 + t]; s = p.x; sq = p.y; }
  for (int m = 1; m <= 32; m <<= 1) { s += __shfl_xor(s, m); sq += __shfl_xor(sq, m); }
  if (t == 0) {
    float mean = s * (1.f / 1048576.f);
    float var = sq * (1.f / 1048576.f) - mean * mean;
    stats[b] = make_float2(mean, rsqrtf(var + 1e-3f));
  }
}

// ---------------- fused GN + QKV projection GEMM ----------------
// M=32768 tokens, N=768 (q|k|v), K=256. BM=128, BN=128, BK=64. 4 waves (2x2), wave=64x64.
// q output pre-scaled by C^-0.5 * log2(e) so attention scores live in exp2 domain.
__global__ __launch_bounds__(256) void k_qkv(
    const float* __restrict__ x, const float* __restrict__ gamma, const float* __restrict__ beta,
    const float* __restrict__ bq, const float* __restrict__ bk, const float* __restrict__ bv,
    const float2* __restrict__ stats, const unsigned short* __restrict__ wT,
    unsigned short* __restrict__ qo, unsigned short* __restrict__ ko, unsigned short* __restrict__ vo)
{
  __shared__ unsigned short As[128 * 64];
  __shared__ unsigned short Bs[128 * 64];
  const int bm = blockIdx.x, bn = blockIdx.y;
  const int mat = bn >> 1, dbase = (bn & 1) * 128;
  const int tid = threadIdx.x, lane = tid & 63, w = tid >> 6;
  const int wm = w >> 1, wn = w & 1;
  const int m0 = bm * 128;
  const float2 st = stats[bm >> 5];
  f32x16 acc[2][2] = {};
  for (int ks = 0; ks < 4; ++ks) {
    // A: x -> GN -> bf16, swizzled LDS [128][64]
    for (int i = 0; i < 8; ++i) {
      int chunk = tid + i * 256;
      int row = chunk >> 4, cq = (chunk & 15) * 4;
      int c = ks * 64 + cq;
      const float4 xv = *(const float4*)(x + (size_t)(m0 + row) * 256 + c);
      const float4 g = *(const float4*)(gamma + c);
      const float4 bt = *(const float4*)(beta + c);
      unsigned short h[4];
      h[0] = f2bf((xv.x - st.x) * st.y * g.x + bt.x);
      h[1] = f2bf((xv.y - st.x) * st.y * g.y + bt.y);
      h[2] = f2bf((xv.z - st.x) * st.y * g.z + bt.z);
      h[3] = f2bf((xv.w - st.x) * st.y * g.w + bt.w);
      *(uint2*)(&As[row * 64 + (cq ^ ((row & 7) << 3))]) = *(uint2*)h;
    }
    // B: wT rows (d) x cols (c), bf16 direct
    for (int i = 0; i < 4; ++i) {
      int chunk = tid + i * 256;
      int row = chunk >> 3, cc = (chunk & 7) * 8;
      const uint4* src = (const uint4*)(wT + (size_t)(mat * 256 + dbase + row) * 256 + ks * 64 + cc);
      *(uint4*)(&Bs[row * 64 + (cc ^ ((row & 7) << 3))]) = *src;
    }
    __syncthreads();
    for (int kk = 0; kk < 4; ++kk) {
      short8 a[2], b[2];
      for (int mi = 0; mi < 2; ++mi) {
        int row = wm * 64 + mi * 32 + (lane & 31);
        int off = (kk * 16 + (lane >> 5) * 8) ^ ((row & 7) << 3);
        a[mi] = *(const short8*)(&As[row * 64 + off]);
      }
      for (int ni = 0; ni < 2; ++ni) {
        int row = wn * 64 + ni * 32 + (lane & 31);
        int off = (kk * 16 + (lane >> 5) * 8) ^ ((row & 7) << 3);
        b[ni] = *(const short8*)(&Bs[row * 64 + off]);
      }
      for (int mi = 0; mi < 2; ++mi)
        for (int ni = 0; ni < 2; ++ni)
          acc[mi][ni] = __builtin_amdgcn_mfma_f32_32x32x16_bf16(a[mi], b[ni], acc[mi][ni], 0, 0, 0);
    }
    __syncthreads();
  }
  const float* bias = (mat == 0) ? bq : (mat == 1) ? bk : bv;
  unsigned short* outp = (mat == 0) ? qo : (mat == 1) ? ko : vo;
  const float qs = 0.09016844005555646f;  // (1/16) * log2(e)
  for (int ni = 0; ni < 2; ++ni) {
    int dcol = dbase + wn * 64 + ni * 32 + (lane & 31);
    float bv_ = bias[dcol];
    for (int mi = 0; mi < 2; ++mi)
      for (int r = 0; r < 16; ++r) {
        int rowD = (r & 3) + 8 * (r >> 2) + 4 * (lane >> 5);
        int token = m0 + wm * 64 + mi * 32 + rowD;
        float v = acc[mi][ni][r] + bv_;
        if (mat == 0) v *= qs;
        outp[(size_t)token * 256 + dcol] = f2bf(v);
      }
  }
}

// ---------------- V transpose: vt[b][d][n] = v[b][n][d] ----------------
__global__ __launch_bounds__(256) void k_vt(const unsigned short* __restrict__ v,
                                            unsigned short* __restrict__ vt) {
  __shared__ unsigned short T[64 * 64];
  int bx = blockIdx.x;
  int batch = bx >> 8;
  int tn = (bx & 255) >> 2, td = bx & 3;
  int n0 = tn * 64, d0 = td * 64;
  int tid = threadIdx.x;
  for (int i = 0; i < 2; ++i) {
    int chunk = tid + i * 256;
    int r = chunk >> 3, cc = (chunk & 7) * 8;
    const uint4* src = (const uint4*)(v + (size_t)(batch * 4096 + n0 + r) * 256 + d0 + cc);
    *(uint4*)(&T[r * 64 + (cc ^ ((r & 7) << 3))]) = *src;
  }
  __syncthreads();
  for (int i = 0; i < 2; ++i) {
    int chunk = tid + i * 256;
    int rd = chunk >> 3, cn = (chunk & 7) * 8;
    unsigned short tmp[8];
    for (int j = 0; j < 8; ++j) {
      int nn = cn + j;
      tmp[j] = T[nn * 64 + (rd ^ ((nn & 7) << 3))];
    }
    *(uint4*)(vt + (size_t)(batch * 256 + d0 + rd) * 4096 + n0 + cn) = *(uint4*)tmp;
  }
}

// ---------------- flash attention ----------------
// grid 256: batch = blockIdx&7 (XCD affinity), 32 q-tiles of 128 rows.
// 8 waves x 16 q-rows, KVBLK=64, 16x16x32 bf16 MFMA, online softmax in exp2 domain.
__global__ __launch_bounds__(512, 2) void k_attn(
    const unsigned short* __restrict__ q, const unsigned short* __restrict__ k,
    const unsigned short* __restrict__ vt, unsigned short* __restrict__ o)
{
  __shared__ unsigned short Ks[64 * 256];   // K tile, swizzled; P regions reuse this
  __shared__ unsigned short Vt[256 * 64];   // V^T tile, swizzled
  const int batch = blockIdx.x & 7, qt = blockIdx.x >> 3;
  const int q0 = qt * 128;
  const int tid = threadIdx.x, lane = tid & 63, w = tid >> 6;
  const int qrow = w * 16 + (lane & 15);
  const size_t qtok = (size_t)(batch * 4096 + q0 + qrow);
  short8 qf[8];
  for (int kt = 0; kt < 8; ++kt)
    qf[kt] = *(const short8*)(q + qtok * 256 + kt * 32 + (lane >> 4) * 8);
  f32x4 acc[16] = {};
  float m_r[4] = {-INFINITY, -INFINITY, -INFINITY, -INFINITY};
  float l_r[4] = {0.f, 0.f, 0.f, 0.f};
  unsigned short* Pw = &Ks[w * 1024];  // per-wave 16x64 P scratch (after QK reads done)

  for (int kv = 0; kv < 64; ++kv) {
    const int k0 = kv * 64;
    for (int i = 0; i < 4; ++i) {  // stage K [64][256]
      int chunk = tid + i * 512;
      int row = chunk >> 5, cc = (chunk & 31) * 8;
      const uint4* src = (const uint4*)(k + (size_t)(batch * 4096 + k0 + row) * 256 + cc);
      *(uint4*)(&Ks[row * 256 + (cc ^ ((row & 7) << 3))]) = *src;
    }
    for (int i = 0; i < 4; ++i) {  // stage V^T [256][64]
      int chunk = tid + i * 512;
      int row = chunk >> 3, cc = (chunk & 7) * 8;
      const uint4* src = (const uint4*)(vt + (size_t)(batch * 256 + row) * 4096 + k0 + cc);
      *(uint4*)(&Vt[row * 64 + (cc ^ ((row & 7) << 3))]) = *src;
    }
    __syncthreads();
    // S = Q K^T (exp2 domain; q pre-scaled)
    f32x4 s[4] = {};
    for (int ct = 0; ct < 4; ++ct)
      for (int kt = 0; kt < 8; ++kt) {
        int rowK = ct * 16 + (lane & 15);
        int off = (kt * 32 + (lane >> 4) * 8) ^ ((rowK & 7) << 3);
        short8 b = *(const short8*)(&Ks[rowK * 256 + off]);
        s[ct] = __builtin_amdgcn_mfma_f32_16x16x32_bf16(qf[kt], b, s[ct], 0, 0, 0);
      }
    // online softmax (rows spread over regs, cols over 16-lane groups)
    float pm[4], rs[4];
    for (int r = 0; r < 4; ++r) {
      pm[r] = fmaxf(fmaxf(s[0][r], s[1][r]), fmaxf(s[2][r], s[3][r]));
      pm[r] = fmaxf(pm[r], __shfl_xor(pm[r], 1));
      pm[r] = fmaxf(pm[r], __shfl_xor(pm[r], 2));
      pm[r] = fmaxf(pm[r], __shfl_xor(pm[r], 4));
      pm[r] = fmaxf(pm[r], __shfl_xor(pm[r], 8));
    }
    float growth = fmaxf(fmaxf(pm[0] - m_r[0], pm[1] - m_r[1]),
                         fmaxf(pm[2] - m_r[2], pm[3] - m_r[3]));
    if (!__all(growth <= 8.0f)) {  // defer-max (T13)
      for (int r = 0; r < 4; ++r) {
        float mn = fmaxf(m_r[r], pm[r]);
        float corr = exp2f(m_r[r] - mn);
        m_r[r] = mn;
        l_r[r] *= corr;
        for (int dt = 0; dt < 16; ++dt) acc[dt][r] *= corr;
      }
    }
    for (int r = 0; r < 4; ++r) rs[r] = 0.f;
    for (int ct = 0; ct < 4; ++ct)
      for (int r = 0; r < 4; ++r) {
        float p = exp2f(s[ct][r] - m_r[r]);
        s[ct][r] = p;
        rs[r] += p;
      }
    for (int r = 0; r < 4; ++r) {
      rs[r] += __shfl_xor(rs[r], 1);
      rs[r] += __shfl_xor(rs[r], 2);
      rs[r] += __shfl_xor(rs[r], 4);
      rs[r] += __shfl_xor(rs[r], 8);
      l_r[r] += rs[r];
    }
    __syncthreads();  // all waves done reading Ks before P overwrites it
    for (int ct = 0; ct < 4; ++ct)
      for (int r = 0; r < 4; ++r) {
        int row = (lane >> 4) * 4 + r;
        int col = ct * 16 + (lane & 15);
        Pw[row * 64 + (col ^ ((row & 7) << 3))] = f2bf(s[ct][r]);
      }
    __syncthreads();  // P visible
    for (int kt2 = 0; kt2 < 2; ++kt2) {
      int rowP = lane & 15;
      int offP = (kt2 * 32 + (lane >> 4) * 8) ^ ((rowP & 7) << 3);
      short8 a = *(const short8*)(&Pw[rowP * 64 + offP]);
      for (int dt = 0; dt < 16; ++dt) {
        int rowd = dt * 16 + (lane & 15);
        int off = (kt2 * 32 + (lane >> 4) * 8) ^ ((rowd & 7) << 3);
        short8 b = *(const short8*)(&Vt[rowd * 64 + off]);
        acc[dt] = __builtin_amdgcn_mfma_f32_16x16x32_bf16(a, b, acc[dt], 0, 0, 0);
      }
    }
    __syncthreads();  // PV done before next stage
  }
  float inv[4];
  for (int r = 0; r < 4; ++r) inv[r] = 1.f / l_r[r];
  for (int dt = 0; dt < 16; ++dt)
    for (int r = 0; r < 4; ++r) {
      int row = (lane >> 4) * 4 + r;
      int tok = batch * 4096 + q0 + w * 16 + row;
      o[(size_t)tok * 256 + dt * 16 + (lane & 15)] = f2bf(acc[dt][r] * inv[r]);
    }
}

// ---------------- output projection + bias + residual ----------------
__global__ __launch_bounds__(256) void k_proj(
    const unsigned short* __restrict__ o, const unsigned short* __restrict__ wT,
    const float* __restrict__ bp, const float* __restrict__ x, float* __restrict__ out)
{
  __shared__ unsigned short As[128 * 64];
  __shared__ unsigned short Bs[128 * 64];
  const int bm = blockIdx.x, bn = blockIdx.y;
  const int dbase = bn * 128;
  const int tid = threadIdx.x, lane = tid & 63, w = tid >> 6;
  const int wm = w >> 1, wn = w & 1;
  const int m0 = bm * 128;
  f32x16 acc[2][2] = {};
  for (int ks = 0; ks < 4; ++ks) {
    for (int i = 0; i < 4; ++i) {
      int chunk = tid + i * 256;
      int row = chunk >> 3, cc = (chunk & 7) * 8;
      const uint4* src = (const uint4*)(o + (size_t)(m0 + row) * 256 + ks * 64 + cc);
      *(uint4*)(&As[row * 64 + (cc ^ ((row & 7) << 3))]) = *src;
    }
    for (int i = 0; i < 4; ++i) {
      int chunk = tid + i * 256;
      int row = chunk >> 3, cc = (chunk & 7) * 8;
      const uint4* src = (const uint4*)(wT + (size_t)(3 * 256 + dbase + row) * 256 + ks * 64 + cc);
      *(uint4*)(&Bs[row * 64 + (cc ^ ((row & 7) << 3))]) = *src;
    }
    __syncthreads();
    for (int kk = 0; kk < 4; ++kk) {
      short8 a[2], b[2];
      for (int mi = 0; mi < 2; ++mi) {
        int row = wm * 64 + mi * 32 + (lane & 31);
        int off = (kk * 16 + (lane >> 5) * 8) ^ ((row & 7) << 3);
        a[mi] = *(const short8*)(&As[row * 64 + off]);
      }
      for (int ni = 0; ni < 2; ++ni) {
        int row = wn * 64 + ni * 32 + (lane & 31);
        int off = (kk * 16 + (lane >> 5) * 8) ^ ((row & 7) << 3);
        b[ni] = *(const short8*)(&Bs[row * 64 + off]);
      }
      for (int mi = 0; mi < 2; ++mi)
        for (int ni = 0; ni < 2; ++ni)
          acc[mi][ni] = __builtin_amdgcn_mfma_f32_32x32x16_bf16(a[mi], b[ni], acc[mi][ni], 0, 0, 0);
    }
    __syncthreads();
  }
  for (int ni = 0; ni < 2; ++ni) {
    int dcol = dbase + wn * 64 + ni * 32 + (lane & 31);
    float bv_ = bp[dcol];
    for (int mi = 0; mi < 2; ++mi)
      for (int r = 0; r < 16; ++r) {
        int rowD = (r & 3) + 8 * (r >> 2) + 4 * (lane >> 5);
        size_t idx = (size_t)(m0 + wm * 64 + mi * 32 + rowD) * 256 + dcol;
        out[idx] = x[idx] + acc[mi][ni][r] + bv_;
      }
  }
}

extern "C" void kernel_launch(void* const* d_in, const int* in_sizes, int n_in,
                              void* d_out, int out_size, void* d_ws, size_t ws_size,
                              hipStream_t stream) {
  const float* x = (const float*)d_in[0];
  const float* gamma = (const float*)d_in[1];
  const float* beta = (const float*)d_in[2];
  const float* wq = (const float*)d_in[3];
  const float* bq = (const float*)d_in[4];
  const float* wk = (const float*)d_in[5];
  const float* bk = (const float*)d_in[6];
  const float* wv = (const float*)d_in[7];
  const float* bv = (const float*)d_in[8];
  const float* wp = (const float*)d_in[9];
  const float* bp = (const float*)d_in[10];
  char* ws = (char*)d_ws;
  float2* part = (float2*)(ws + WS_PART);
  float2* stats = (float2*)(ws + WS_STATS);
  unsigned short* wT = (unsigned short*)(ws + WS_WT);
  unsigned short* qw = (unsigned short*)(ws + WS_Q);
  unsigned short* kw = (unsigned short*)(ws + WS_K);
  unsigned short* vw = (unsigned short*)(ws + WS_V);
  unsigned short* vtw = (unsigned short*)(ws + WS_VT);
  unsigned short* ow = (unsigned short*)(ws + WS_O);
  float* out = (float*)d_out;

  k_wt<<<1024, 256, 0, stream>>>(wq, wk, wv, wp, wT);
  k_gn_part<<<256, 256, 0, stream>>>(x, part);
  k_gn_stats<<<8, 64, 0, stream>>>(part, stats);
  k_qkv<<<dim3(256, 6), 256, 0, stream>>>(x, gamma, beta, bq, bk, bv, stats, wT, qw, kw, vw);
  k_vt<<<2048, 256, 0, stream>>>(vw, vtw);
  k_attn<<<256, 512, 0, stream>>>(qw, kw, vtw, ow);
  k_proj<<<dim3(256, 2), 256, 0, stream>>>(ow, wT, bp, x, out);
}

// Round 2
// 308.185 us; speedup vs baseline: 1.0616x; 1.0616x over previous
//
#include <hip/hip_runtime.h>
#include <hip/hip_bf16.h>

typedef __attribute__((ext_vector_type(8))) short short8;
typedef __attribute__((ext_vector_type(4))) float f32x4;
typedef __attribute__((ext_vector_type(16))) float f32x16;

#define WS_PART 0u          // 256 * float2 partials
#define WS_STATS 4096u      // 8 * float2 (mean, rstd)
#define WS_WT 8192u         // 4*256*256 bf16 = 512KB
#define WS_Q  (1u<<20)
#define WS_K  (WS_Q + 16777216u)
#define WS_V  (WS_K + 16777216u)
#define WS_VT (WS_V + 16777216u)
#define WS_O  (WS_VT + 16777216u)

__device__ __forceinline__ unsigned short f2bf(float f) {
  unsigned int u = __builtin_bit_cast(unsigned int, f);
  u += 0x7fffu + ((u >> 16) & 1u);
  return (unsigned short)(u >> 16);
}

__device__ __forceinline__ void gl_lds16(const unsigned short* g, unsigned short* l) {
  __builtin_amdgcn_global_load_lds(
      (const __attribute__((address_space(1))) unsigned int*)g,
      (__attribute__((address_space(3))) unsigned int*)l, 16, 0, 0);
}

// ---------------- weight transpose: wT[m][d][c] = bf16(w_m[c][d]) ----------------
__global__ void k_wt(const float* __restrict__ wq, const float* __restrict__ wk,
                     const float* __restrict__ wv, const float* __restrict__ wp,
                     unsigned short* __restrict__ wT) {
  int m = blockIdx.x >> 8;
  int c = blockIdx.x & 255;
  const float* w = (m == 0) ? wq : (m == 1) ? wk : (m == 2) ? wv : wp;
  int d = threadIdx.x;
  wT[(size_t)(m * 256 + d) * 256 + c] = f2bf(w[c * 256 + d]);
}

// ---------------- GroupNorm stats (per batch over 1M elements) ----------------
__global__ void k_gn_part(const float* __restrict__ x, float2* __restrict__ part) {
  int b = blockIdx.x >> 5, seg = blockIdx.x & 31;
  const float4* xp = (const float4*)(x + ((size_t)b << 20) + ((size_t)seg << 15));
  float s = 0.f, sq = 0.f;
  for (int i = 0; i < 32; ++i) {
    float4 v = xp[threadIdx.x + i * 256];
    s += v.x + v.y + v.z + v.w;
    sq += v.x * v.x + v.y * v.y + v.z * v.z + v.w * v.w;
  }
  for (int m = 1; m <= 32; m <<= 1) { s += __shfl_xor(s, m); sq += __shfl_xor(sq, m); }
  __shared__ float2 red[4];
  int w = threadIdx.x >> 6;
  if ((threadIdx.x & 63) == 0) red[w] = make_float2(s, sq);
  __syncthreads();
  if (threadIdx.x == 0) {
    float S = 0.f, Q = 0.f;
    for (int i = 0; i < 4; ++i) { S += red[i].x; Q += red[i].y; }
    part[blockIdx.x] = make_float2(S, Q);
  }
}

__global__ void k_gn_stats(const float2* __restrict__ part, float2* __restrict__ stats) {
  int b = blockIdx.x, t = threadIdx.x;
  float s = 0.f, sq = 0.f;
  if (t < 32) { float2 p = part[b * 32 + t]; s = p.x; sq = p.y; }
  for (int m = 1; m <= 32; m <<= 1) { s += __shfl_xor(s, m); sq += __shfl_xor(sq, m); }
  if (t == 0) {
    float mean = s * (1.f / 1048576.f);
    float var = sq * (1.f / 1048576.f) - mean * mean;
    stats[b] = make_float2(mean, rsqrtf(var + 1e-3f));
  }
}

// ---------------- fused GN + QKV projection GEMM ----------------
__global__ __launch_bounds__(256) void k_qkv(
    const float* __restrict__ x, const float* __restrict__ gamma, const float* __restrict__ beta,
    const float* __restrict__ bq, const float* __restrict__ bk, const float* __restrict__ bv,
    const float2* __restrict__ stats, const unsigned short* __restrict__ wT,
    unsigned short* __restrict__ qo, unsigned short* __restrict__ ko, unsigned short* __restrict__ vo)
{
  __shared__ unsigned short As[128 * 64];
  __shared__ unsigned short Bs[128 * 64];
  const int bm = blockIdx.x, bn = blockIdx.y;
  const int mat = bn >> 1, dbase = (bn & 1) * 128;
  const int tid = threadIdx.x, lane = tid & 63, w = tid >> 6;
  const int wm = w >> 1, wn = w & 1;
  const int m0 = bm * 128;
  const float2 st = stats[bm >> 5];
  f32x16 acc[2][2] = {};
  for (int ks = 0; ks < 4; ++ks) {
    for (int i = 0; i < 8; ++i) {
      int chunk = tid + i * 256;
      int row = chunk >> 4, cq = (chunk & 15) * 4;
      int c = ks * 64 + cq;
      const float4 xv = *(const float4*)(x + (size_t)(m0 + row) * 256 + c);
      const float4 g = *(const float4*)(gamma + c);
      const float4 bt = *(const float4*)(beta + c);
      unsigned short h[4];
      h[0] = f2bf((xv.x - st.x) * st.y * g.x + bt.x);
      h[1] = f2bf((xv.y - st.x) * st.y * g.y + bt.y);
      h[2] = f2bf((xv.z - st.x) * st.y * g.z + bt.z);
      h[3] = f2bf((xv.w - st.x) * st.y * g.w + bt.w);
      *(uint2*)(&As[row * 64 + (cq ^ ((row & 7) << 3))]) = *(uint2*)h;
    }
    for (int i = 0; i < 4; ++i) {
      int chunk = tid + i * 256;
      int row = chunk >> 3, cc = (chunk & 7) * 8;
      const uint4* src = (const uint4*)(wT + (size_t)(mat * 256 + dbase + row) * 256 + ks * 64 + cc);
      *(uint4*)(&Bs[row * 64 + (cc ^ ((row & 7) << 3))]) = *src;
    }
    __syncthreads();
    for (int kk = 0; kk < 4; ++kk) {
      short8 a[2], b[2];
      for (int mi = 0; mi < 2; ++mi) {
        int row = wm * 64 + mi * 32 + (lane & 31);
        int off = (kk * 16 + (lane >> 5) * 8) ^ ((row & 7) << 3);
        a[mi] = *(const short8*)(&As[row * 64 + off]);
      }
      for (int ni = 0; ni < 2; ++ni) {
        int row = wn * 64 + ni * 32 + (lane & 31);
        int off = (kk * 16 + (lane >> 5) * 8) ^ ((row & 7) << 3);
        b[ni] = *(const short8*)(&Bs[row * 64 + off]);
      }
      for (int mi = 0; mi < 2; ++mi)
        for (int ni = 0; ni < 2; ++ni)
          acc[mi][ni] = __builtin_amdgcn_mfma_f32_32x32x16_bf16(a[mi], b[ni], acc[mi][ni], 0, 0, 0);
    }
    __syncthreads();
  }
  const float* bias = (mat == 0) ? bq : (mat == 1) ? bk : bv;
  unsigned short* outp = (mat == 0) ? qo : (mat == 1) ? ko : vo;
  const float qs = 0.09016844005555646f;  // (1/16) * log2(e)
  for (int ni = 0; ni < 2; ++ni) {
    int dcol = dbase + wn * 64 + ni * 32 + (lane & 31);
    float bv_ = bias[dcol];
    for (int mi = 0; mi < 2; ++mi)
      for (int r = 0; r < 16; ++r) {
        int rowD = (r & 3) + 8 * (r >> 2) + 4 * (lane >> 5);
        int token = m0 + wm * 64 + mi * 32 + rowD;
        float v = acc[mi][ni][r] + bv_;
        if (mat == 0) v *= qs;
        outp[(size_t)token * 256 + dcol] = f2bf(v);
      }
  }
}

// ---------------- V transpose: vt[b][d][n] = v[b][n][d] ----------------
__global__ __launch_bounds__(256) void k_vt(const unsigned short* __restrict__ v,
                                            unsigned short* __restrict__ vt) {
  __shared__ unsigned short T[64 * 64];
  int bx = blockIdx.x;
  int batch = bx >> 8;
  int tn = (bx & 255) >> 2, td = bx & 3;
  int n0 = tn * 64, d0 = td * 64;
  int tid = threadIdx.x;
  for (int i = 0; i < 2; ++i) {
    int chunk = tid + i * 256;
    int r = chunk >> 3, cc = (chunk & 7) * 8;
    const uint4* src = (const uint4*)(v + (size_t)(batch * 4096 + n0 + r) * 256 + d0 + cc);
    *(uint4*)(&T[r * 64 + (cc ^ ((r & 7) << 3))]) = *src;
  }
  __syncthreads();
  for (int i = 0; i < 2; ++i) {
    int chunk = tid + i * 256;
    int rd = chunk >> 3, cn = (chunk & 7) * 8;
    unsigned short tmp[8];
    for (int j = 0; j < 8; ++j) {
      int nn = cn + j;
      tmp[j] = T[nn * 64 + (rd ^ ((nn & 7) << 3))];
    }
    *(uint4*)(vt + (size_t)(batch * 256 + d0 + rd) * 4096 + n0 + cn) = *(uint4*)tmp;
  }
}

// ---------------- flash attention ----------------
// 512 blocks (2/CU): batch = blockIdx&7 (XCD affinity), 64 q-tiles of 64 rows.
// 4 waves x 16 q-rows, KVBLK=64. global_load_lds staging (pre-swizzled source),
// per-wave P scratch (no barrier for P), 2 barriers/iter, setprio around MFMA.
__global__ __launch_bounds__(256, 2) void k_attn(
    const unsigned short* __restrict__ q, const unsigned short* __restrict__ k,
    const unsigned short* __restrict__ vt, unsigned short* __restrict__ o)
{
  __shared__ unsigned short Ks[64 * 256];   // K tile (content swizzled via source)
  __shared__ unsigned short Vt[256 * 64];   // V^T tile (content swizzled via source)
  __shared__ unsigned short Ps[4][16 * 64]; // per-wave P scratch
  const int batch = blockIdx.x & 7, qt = blockIdx.x >> 3;
  const int q0 = qt * 64;
  const int tid = threadIdx.x, lane = tid & 63, w = tid >> 6;
  const int qrow = w * 16 + (lane & 15);
  const size_t qtok = (size_t)(batch * 4096 + q0 + qrow);
  short8 qf[8];
  for (int kt = 0; kt < 8; ++kt)
    qf[kt] = *(const short8*)(q + qtok * 256 + kt * 32 + (lane >> 4) * 8);
  f32x4 acc[16] = {};
  float m_r[4] = {-INFINITY, -INFINITY, -INFINITY, -INFINITY};
  float l_r[4] = {0.f, 0.f, 0.f, 0.f};
  unsigned short* Pw = Ps[w];

  // iter-invariant per-lane staging offsets (elements); source pre-swizzled so
  // linear global_load_lds dest + swizzled read agree (both-sides involution).
  unsigned koff[8], voff[8];
#pragma unroll
  for (int i = 0; i < 8; ++i) {
    int krow = w * 16 + i * 2 + (lane >> 5);            // 0..63
    koff[i] = krow * 256 + ((((lane & 31) ^ (krow & 7))) << 3);
    int vrow = w * 64 + i * 8 + (lane >> 3);            // 0..255 (d)
    voff[i] = vrow * 4096 + ((((lane & 7) ^ (vrow & 7))) << 3);
  }
  const unsigned short* kb = k + (size_t)batch * 4096 * 256;   // advances 64*256/iter
  const unsigned short* vb = vt + (size_t)batch * 256 * 4096;  // advances 64/iter

#define STAGE() do {                                            \
    _Pragma("unroll")                                           \
    for (int i = 0; i < 8; ++i)                                 \
      gl_lds16(kb + koff[i], &Ks[(w * 16 + i * 2) * 256]);      \
    _Pragma("unroll")                                           \
    for (int i = 0; i < 8; ++i)                                 \
      gl_lds16(vb + voff[i], &Vt[(w * 64 + i * 8) * 64]);       \
  } while (0)

  STAGE();
  for (int kv = 0; kv < 64; ++kv) {
    __syncthreads();  // stage complete (compiler drains vmcnt before barrier)
    // S = Q K^T (exp2 domain; q pre-scaled)
    f32x4 s[4] = {};
    __builtin_amdgcn_s_setprio(1);
    for (int ct = 0; ct < 4; ++ct)
      for (int kt = 0; kt < 8; ++kt) {
        int rowK = ct * 16 + (lane & 15);
        int off = (kt * 32 + (lane >> 4) * 8) ^ ((rowK & 7) << 3);
        short8 b = *(const short8*)(&Ks[rowK * 256 + off]);
        s[ct] = __builtin_amdgcn_mfma_f32_16x16x32_bf16(qf[kt], b, s[ct], 0, 0, 0);
      }
    __builtin_amdgcn_s_setprio(0);
    // online softmax
    float pm[4], rs[4];
    for (int r = 0; r < 4; ++r) {
      pm[r] = fmaxf(fmaxf(s[0][r], s[1][r]), fmaxf(s[2][r], s[3][r]));
      pm[r] = fmaxf(pm[r], __shfl_xor(pm[r], 1));
      pm[r] = fmaxf(pm[r], __shfl_xor(pm[r], 2));
      pm[r] = fmaxf(pm[r], __shfl_xor(pm[r], 4));
      pm[r] = fmaxf(pm[r], __shfl_xor(pm[r], 8));
    }
    float growth = fmaxf(fmaxf(pm[0] - m_r[0], pm[1] - m_r[1]),
                         fmaxf(pm[2] - m_r[2], pm[3] - m_r[3]));
    if (!__all(growth <= 8.0f)) {  // defer-max (T13)
      for (int r = 0; r < 4; ++r) {
        float mn = fmaxf(m_r[r], pm[r]);
        float corr = exp2f(m_r[r] - mn);
        m_r[r] = mn;
        l_r[r] *= corr;
        for (int dt = 0; dt < 16; ++dt) acc[dt][r] *= corr;
      }
    }
    for (int r = 0; r < 4; ++r) rs[r] = 0.f;
    for (int ct = 0; ct < 4; ++ct)
      for (int r = 0; r < 4; ++r) {
        float p = exp2f(s[ct][r] - m_r[r]);
        s[ct][r] = p;
        rs[r] += p;
      }
    for (int r = 0; r < 4; ++r) {
      rs[r] += __shfl_xor(rs[r], 1);
      rs[r] += __shfl_xor(rs[r], 2);
      rs[r] += __shfl_xor(rs[r], 4);
      rs[r] += __shfl_xor(rs[r], 8);
      l_r[r] += rs[r];
    }
    // P -> per-wave LDS (same-wave write->read: compiler handles lgkmcnt, no barrier)
    for (int ct = 0; ct < 4; ++ct)
      for (int r = 0; r < 4; ++r) {
        int row = (lane >> 4) * 4 + r;
        int col = ct * 16 + (lane & 15);
        Pw[row * 64 + (col ^ ((row & 7) << 3))] = f2bf(s[ct][r]);
      }
    __builtin_amdgcn_s_setprio(1);
    for (int kt2 = 0; kt2 < 2; ++kt2) {
      int rowP = lane & 15;
      int offP = (kt2 * 32 + (lane >> 4) * 8) ^ ((rowP & 7) << 3);
      short8 a = *(const short8*)(&Pw[rowP * 64 + offP]);
      for (int dt = 0; dt < 16; ++dt) {
        int rowd = dt * 16 + (lane & 15);
        int off = (kt2 * 32 + (lane >> 4) * 8) ^ ((rowd & 7) << 3);
        short8 b = *(const short8*)(&Vt[rowd * 64 + off]);
        acc[dt] = __builtin_amdgcn_mfma_f32_16x16x32_bf16(a, b, acc[dt], 0, 0, 0);
      }
    }
    __builtin_amdgcn_s_setprio(0);
    __syncthreads();  // all waves done reading Ks/Vt before next stage
    if (kv < 63) {
      kb += 64 * 256;
      vb += 64;
      STAGE();
    }
  }
#undef STAGE
  float inv[4];
  for (int r = 0; r < 4; ++r) inv[r] = 1.f / l_r[r];
  for (int dt = 0; dt < 16; ++dt)
    for (int r = 0; r < 4; ++r) {
      int row = (lane >> 4) * 4 + r;
      int tok = batch * 4096 + q0 + w * 16 + row;
      o[(size_t)tok * 256 + dt * 16 + (lane & 15)] = f2bf(acc[dt][r] * inv[r]);
    }
}

// ---------------- output projection + bias + residual ----------------
__global__ __launch_bounds__(256) void k_proj(
    const unsigned short* __restrict__ o, const unsigned short* __restrict__ wT,
    const float* __restrict__ bp, const float* __restrict__ x, float* __restrict__ out)
{
  __shared__ unsigned short As[128 * 64];
  __shared__ unsigned short Bs[128 * 64];
  const int bm = blockIdx.x, bn = blockIdx.y;
  const int dbase = bn * 128;
  const int tid = threadIdx.x, lane = tid & 63, w = tid >> 6;
  const int wm = w >> 1, wn = w & 1;
  const int m0 = bm * 128;
  f32x16 acc[2][2] = {};
  for (int ks = 0; ks < 4; ++ks) {
    for (int i = 0; i < 4; ++i) {
      int chunk = tid + i * 256;
      int row = chunk >> 3, cc = (chunk & 7) * 8;
      const uint4* src = (const uint4*)(o + (size_t)(m0 + row) * 256 + ks * 64 + cc);
      *(uint4*)(&As[row * 64 + (cc ^ ((row & 7) << 3))]) = *src;
    }
    for (int i = 0; i < 4; ++i) {
      int chunk = tid + i * 256;
      int row = chunk >> 3, cc = (chunk & 7) * 8;
      const uint4* src = (const uint4*)(wT + (size_t)(3 * 256 + dbase + row) * 256 + ks * 64 + cc);
      *(uint4*)(&Bs[row * 64 + (cc ^ ((row & 7) << 3))]) = *src;
    }
    __syncthreads();
    for (int kk = 0; kk < 4; ++kk) {
      short8 a[2], b[2];
      for (int mi = 0; mi < 2; ++mi) {
        int row = wm * 64 + mi * 32 + (lane & 31);
        int off = (kk * 16 + (lane >> 5) * 8) ^ ((row & 7) << 3);
        a[mi] = *(const short8*)(&As[row * 64 + off]);
      }
      for (int ni = 0; ni < 2; ++ni) {
        int row = wn * 64 + ni * 32 + (lane & 31);
        int off = (kk * 16 + (lane >> 5) * 8) ^ ((row & 7) << 3);
        b[ni] = *(const short8*)(&Bs[row * 64 + off]);
      }
      for (int mi = 0; mi < 2; ++mi)
        for (int ni = 0; ni < 2; ++ni)
          acc[mi][ni] = __builtin_amdgcn_mfma_f32_32x32x16_bf16(a[mi], b[ni], acc[mi][ni], 0, 0, 0);
    }
    __syncthreads();
  }
  for (int ni = 0; ni < 2; ++ni) {
    int dcol = dbase + wn * 64 + ni * 32 + (lane & 31);
    float bv_ = bp[dcol];
    for (int mi = 0; mi < 2; ++mi)
      for (int r = 0; r < 16; ++r) {
        int rowD = (r & 3) + 8 * (r >> 2) + 4 * (lane >> 5);
        size_t idx = (size_t)(m0 + wm * 64 + mi * 32 + rowD) * 256 + dcol;
        out[idx] = x[idx] + acc[mi][ni][r] + bv_;
      }
  }
}

extern "C" void kernel_launch(void* const* d_in, const int* in_sizes, int n_in,
                              void* d_out, int out_size, void* d_ws, size_t ws_size,
                              hipStream_t stream) {
  const float* x = (const float*)d_in[0];
  const float* gamma = (const float*)d_in[1];
  const float* beta = (const float*)d_in[2];
  const float* wq = (const float*)d_in[3];
  const float* bq = (const float*)d_in[4];
  const float* wk = (const float*)d_in[5];
  const float* bk = (const float*)d_in[6];
  const float* wv = (const float*)d_in[7];
  const float* bv = (const float*)d_in[8];
  const float* wp = (const float*)d_in[9];
  const float* bp = (const float*)d_in[10];
  char* ws = (char*)d_ws;
  float2* part = (float2*)(ws + WS_PART);
  float2* stats = (float2*)(ws + WS_STATS);
  unsigned short* wT = (unsigned short*)(ws + WS_WT);
  unsigned short* qw = (unsigned short*)(ws + WS_Q);
  unsigned short* kw = (unsigned short*)(ws + WS_K);
  unsigned short* vw = (unsigned short*)(ws + WS_V);
  unsigned short* vtw = (unsigned short*)(ws + WS_VT);
  unsigned short* ow = (unsigned short*)(ws + WS_O);
  float* out = (float*)d_out;

  k_wt<<<1024, 256, 0, stream>>>(wq, wk, wv, wp, wT);
  k_gn_part<<<256, 256, 0, stream>>>(x, part);
  k_gn_stats<<<8, 64, 0, stream>>>(part, stats);
  k_qkv<<<dim3(256, 6), 256, 0, stream>>>(x, gamma, beta, bq, bk, bv, stats, wT, qw, kw, vw);
  k_vt<<<2048, 256, 0, stream>>>(vw, vtw);
  k_attn<<<512, 256, 0, stream>>>(qw, kw, vtw, ow);
  k_proj<<<dim3(256, 2), 256, 0, stream>>>(ow, wT, bp, x, out);
}